// Round 7
// baseline (100.314 us; speedup 1.0000x reference)
//
#include <hip/hip_runtime.h>
#include <math.h>

#define N_PTS    65536
#define N_CTR    1024      // per set
#define NCELLS   256       // 16x16 spatial cells
#define CELL_CAP 512
#define CHUNK    512       // centers per block -> 2 chunks per set
#define CUT      44.0f     // cull threshold (log2 units): e < 2^-44 dropped

#define LOG2E 1.4426950408889634f

#if __has_builtin(__builtin_amdgcn_exp2f)
#define EXP2(v) __builtin_amdgcn_exp2f(v)
#else
#define EXP2(v) exp2f(v)
#endif

// ws layout:
//   RA[3072] float4 : (zb, zc, zd, ze)  poly coeffs, log2e folded
//   RB[3072] float4 : (za, k0, k1, k2)
//   RC[3072] float  : k3 (set0 only, else 0)
//   RT[3072] float4 : (cx, cy, d1*L, d2*L)  cull data
//   cnt[256] u32    : per-cell point count
//   idx[256*512] u16: per-cell point indices
// s = za + zb*x + zc*x^2 + zd*y + ze*y^2 (Horner); e = exp2(s)
// set0: ux = x*S(k0 e)+S(k1 e), uy = y*S(k2 e)+S(k3 e)
// set1: P = S(k0 e), Px = x*S(k1 e)+S(k2 e);  set2: Q, Qy analog.

__global__ __launch_bounds__(256) void prep_kernel(
    const float* __restrict__ h0, const float* __restrict__ c0, const float* __restrict__ w0,
    const float* __restrict__ h1, const float* __restrict__ c1, const float* __restrict__ w1,
    const float* __restrict__ h2, const float* __restrict__ c2, const float* __restrict__ w2,
    float4* __restrict__ RA, float4* __restrict__ RB, float* __restrict__ RC,
    float4* __restrict__ RT, unsigned int* __restrict__ cnt,
    float4* __restrict__ out_zero)
{
    const int idx = blockIdx.x * 256 + threadIdx.x;   // 0..3071

    // zero outputs: 3072 threads x 32 float4 = 393216 floats
    {
        float4 z = make_float4(0.f, 0.f, 0.f, 0.f);
        float4* o = out_zero + idx * 32;
        #pragma unroll
        for (int t = 0; t < 32; ++t) o[t] = z;
    }
    if (idx < NCELLS) cnt[idx] = 0u;

    if (idx >= 3 * N_CTR) return;
    const int set = idx >> 10;
    const int j   = idx & (N_CTR - 1);

    const float*  h = (set == 0) ? h0 : ((set == 1) ? h1 : h2);
    const float2* c = (const float2*)((set == 0) ? c0 : ((set == 1) ? c1 : c2));
    const float2* w = (const float2*)((set == 0) ? w0 : ((set == 1) ? w1 : w2));

    float2 cj = c[j];
    float2 wj = w[j];
    float  hh = h[j];
    float d1 = wj.x * wj.x;
    float d2 = wj.y * wj.y;
    float zb =  2.f * cj.x * d1 * LOG2E;
    float zc = -d1 * LOG2E;
    float zd =  2.f * cj.y * d2 * LOG2E;
    float ze = -d2 * LOG2E;
    float za = -(cj.x * cj.x * d1 + cj.y * cj.y * d2) * LOG2E;
    float k0, k1, k2, k3;
    if (set == 0) {
        k0 = -2.f * hh * d1;  k1 = 2.f * hh * d1 * cj.x;
        k2 = -2.f * hh * d2;  k3 = 2.f * hh * d2 * cj.y;
    } else if (set == 1) {
        k0 = hh;  k1 = -2.f * hh * d1;  k2 = 2.f * hh * d1 * cj.x;  k3 = 0.f;
    } else {
        k0 = hh;  k1 = -2.f * hh * d2;  k2 = 2.f * hh * d2 * cj.y;  k3 = 0.f;
    }
    RA[idx] = make_float4(zb, zc, zd, ze);
    RB[idx] = make_float4(za, k0, k1, k2);
    RC[idx] = k3;
    RT[idx] = make_float4(cj.x, cj.y, d1 * LOG2E, d2 * LOG2E);
}

__global__ __launch_bounds__(256) void bucket_kernel(
    const float* __restrict__ x,
    unsigned int* __restrict__ cnt,
    unsigned short* __restrict__ idxl)
{
    const int i = blockIdx.x * 256 + threadIdx.x;   // 65536
    float2 p = ((const float2*)x)[i];
    int cx = (int)(p.x * 16.f); cx = cx > 15 ? 15 : (cx < 0 ? 0 : cx);
    int cy = (int)(p.y * 16.f); cy = cy > 15 ? 15 : (cy < 0 ? 0 : cy);
    const int cell = cy * 16 + cx;
    unsigned int slot = atomicAdd(&cnt[cell], 1u);
    if (slot < CELL_CAP) idxl[cell * CELL_CAP + slot] = (unsigned short)i;
}

__global__ __launch_bounds__(256) void srbf_main(
    const float* __restrict__ x,
    const float4* __restrict__ RA,
    const float4* __restrict__ RB,
    const float*  __restrict__ RC,
    const float4* __restrict__ RT,
    const unsigned int* __restrict__ cnt,
    const unsigned short* __restrict__ idxl,
    float* __restrict__ out)
{
    __shared__ unsigned short list[CHUNK];
    __shared__ int mcnt;

    const int bid   = blockIdx.x;       // 0..1535
    const int set   = bid / 512;
    const int r     = bid & 511;
    const int cell  = r >> 1;
    const int chunk = r & 1;
    const int tid   = threadIdx.x;
    const int lane  = tid & 63;
    const int wv    = tid >> 6;
    const int cbase = set * N_CTR + chunk * CHUNK;

    if (tid == 0) mcnt = 0;
    __syncthreads();

    // geometric cell bounds (deterministic cull set)
    const float cx0 = (float)(cell & 15) * 0.0625f;
    const float cy0 = (float)(cell >> 4) * 0.0625f;
    const float cx1 = cx0 + 0.0625f;
    const float cy1 = cy0 + 0.0625f;

    // ---- phase 1: lane-parallel cull of this chunk's 512 centers ----
    #pragma unroll
    for (int rnd = 0; rnd < 2; ++rnd) {
        const int jl = wv * 128 + rnd * 64 + lane;   // 0..511
        float4 T = RT[cbase + jl];
        float dxm = fmaxf(fmaxf(cx0 - T.x, T.x - cx1), 0.f);
        float dym = fmaxf(fmaxf(cy0 - T.y, T.y - cy1), 0.f);
        float qm  = dxm * dxm * T.z + dym * dym * T.w;
        const bool live = qm < CUT;
        unsigned long long mask = __ballot(live);
        int prefix = __popcll(mask & ((1ull << lane) - 1ull));
        int basep = 0;
        if (lane == 0) basep = atomicAdd(&mcnt, __popcll(mask));
        basep = __shfl(basep, 0);
        if (live) list[basep + prefix] = (unsigned short)jl;
    }
    __syncthreads();
    const int m = mcnt;

    // ---- load this thread's (up to) 2 points ----
    const unsigned int nc = cnt[cell];
    const int n = (int)(nc < CELL_CAP ? nc : CELL_CAP);
    const int t1i = tid, t2i = tid + 256;
    const bool v1 = t1i < n, v2 = t2i < n;
    float x1 = 99.f, y1 = 99.f, x2 = 99.f, y2 = 99.f;
    int o1 = 0, o2 = 0;
    if (v1) { o1 = idxl[cell * CELL_CAP + t1i]; float2 p = ((const float2*)x)[o1]; x1 = p.x; y1 = p.y; }
    if (v2) { o2 = idxl[cell * CELL_CAP + t2i]; float2 p = ((const float2*)x)[o2]; x2 = p.x; y2 = p.y; }

    float A0 = 0.f, A1 = 0.f, A2 = 0.f, A3 = 0.f;
    float B0 = 0.f, B1 = 0.f, B2 = 0.f, B3 = 0.f;

    // ---- phase 2: only live centers; uniform constants (s_load) ----
    #pragma unroll 2
    for (int t = 0; t < m; ++t) {
        const int j = __builtin_amdgcn_readfirstlane(cbase + (int)list[t]);
        const float4 A  = RA[j];
        const float4 B  = RB[j];
        const float  k3 = RC[j];
        {
            float u1 = fmaf(x1, A.y, A.x);
            float u2 = fmaf(x1, u1,  B.x);
            float u3 = fmaf(y1, A.w, A.z);
            float s  = fmaf(y1, u3,  u2);
            float e  = EXP2(s);
            A0 = fmaf(B.y, e, A0);
            A1 = fmaf(B.z, e, A1);
            A2 = fmaf(B.w, e, A2);
            A3 = fmaf(k3,  e, A3);
        }
        if (v2) {
            float u1 = fmaf(x2, A.y, A.x);
            float u2 = fmaf(x2, u1,  B.x);
            float u3 = fmaf(y2, A.w, A.z);
            float s  = fmaf(y2, u3,  u2);
            float e  = EXP2(s);
            B0 = fmaf(B.y, e, B0);
            B1 = fmaf(B.z, e, B1);
            B2 = fmaf(B.w, e, B2);
            B3 = fmaf(k3,  e, B3);
        }
    }

    // ---- epilogue: atomic combine (2 chunks per (set,cell)) ----
    float* obase = out + (size_t)set * 2 * N_PTS;
    if (v1) {
        float r1, r2;
        if (set == 0)      { r1 = fmaf(x1, A0, A1); r2 = fmaf(y1, A2, A3); }
        else if (set == 1) { r1 = A0;               r2 = fmaf(x1, A1, A2); }
        else               { r1 = A0;               r2 = fmaf(y1, A1, A2); }
        atomicAdd(&obase[o1],         r1);
        atomicAdd(&obase[N_PTS + o1], r2);
    }
    if (v2) {
        float r1, r2;
        if (set == 0)      { r1 = fmaf(x2, B0, B1); r2 = fmaf(y2, B2, B3); }
        else if (set == 1) { r1 = B0;               r2 = fmaf(x2, B1, B2); }
        else               { r1 = B0;               r2 = fmaf(y2, B1, B2); }
        atomicAdd(&obase[o2],         r1);
        atomicAdd(&obase[N_PTS + o2], r2);
    }
}

extern "C" void kernel_launch(void* const* d_in, const int* in_sizes, int n_in,
                              void* d_out, int out_size, void* d_ws, size_t ws_size,
                              hipStream_t stream) {
    const float* x  = (const float*)d_in[0];
    const float* h1 = (const float*)d_in[1];
    const float* c1 = (const float*)d_in[2];
    const float* w1 = (const float*)d_in[3];
    const float* h2 = (const float*)d_in[4];
    const float* c2 = (const float*)d_in[5];
    const float* w2 = (const float*)d_in[6];
    const float* h3 = (const float*)d_in[7];
    const float* c3 = (const float*)d_in[8];
    const float* w3 = (const float*)d_in[9];

    char* ws = (char*)d_ws;
    float4* RA = (float4*)(ws);                         // 49152 B
    float4* RB = (float4*)(ws + 49152);                 // 49152 B
    float*  RC = (float*) (ws + 98304);                 // 12288 B
    float4* RT = (float4*)(ws + 110592);                // 49152 B
    unsigned int*   cnt  = (unsigned int*)(ws + 159744);   // 1024 B
    unsigned short* idxl = (unsigned short*)(ws + 160768); // 262144 B  (total ~423 KB)

    // K1: fold constants + zero outputs + zero cell counts
    prep_kernel<<<dim3(12), dim3(256), 0, stream>>>(
        h1, c1, w1, h2, c2, w2, h3, c3, w3, RA, RB, RC, RT, cnt, (float4*)d_out);

    // K2: bucket points into 16x16 cells
    bucket_kernel<<<dim3(256), dim3(256), 0, stream>>>(x, cnt, idxl);

    // K3: 3 sets x 256 cells x 2 center-chunks = 1536 blocks
    srbf_main<<<dim3(1536), dim3(256), 0, stream>>>(
        x, RA, RB, RC, RT, cnt, idxl, (float*)d_out);
}